// Round 14
// baseline (2687.002 us; speedup 1.0000x reference)
//
#include <hip/hip_runtime.h>
#include <math.h>

typedef __bf16 bf;
typedef __attribute__((ext_vector_type(4))) __bf16 bfv4;
typedef __attribute__((ext_vector_type(8))) __bf16 bfv8;
typedef __attribute__((ext_vector_type(4))) float f32x4;

__device__ __forceinline__ void gload16(const void* g, void* l) {
  __builtin_amdgcn_global_load_lds((const __attribute__((address_space(1))) void*)g,
                                   (__attribute__((address_space(3))) void*)l, 16, 0, 0);
}

// ---------------- generalized GEMM op descriptor ----------------
// C[M,N] = A[M,K] * Bt[N,K]^T, bf16 in, f32 accum, 128x128 tile, BK=32.
// A row addr: (row>>9)*lMa + (row&511)*la ; K addr: blk*lK + (k&511),
// blk = (k>>9) + z*kz. Z: A += (z>>zshA)*sAz, B += (z&zmskB)*sBz, C += z*sCz.
// tMASK=1: causal im2col (valid iff (row&15) >= blk), zero-page redirect.
// tMASK=2: scan shift (valid iff (row&63) >= maskCmp), zero-page redirect.
// tMASK=3: Toeplitz conv: A elem(row=t, k=s) = pvec[c*2065 + 1023 - t + s],
//          c=(t+1)&7; causal => per-tile K clamp to m0+128.
// tSHW: bf16 store shifted to row+1, skipping (row&63)==63 (scan-state shift).
struct GOp {
  const bf* A; long la, lKa, lMa, sAz; int zshA, kzA;
  const bf* B; long lb, lKb, sBz; int zmskB, kzB;
  float* C; long ldc, sCz;
  bf* Cb; long ldcb, sCbz;
  const float* bias; int K, maskCmp, mBlk, spS;
};

template<int tB,int tF32,int tB16,int tMASK,int tACC,int tSHW=0>
__device__ __forceinline__ void gbody(const GOp g, int z, long m0, long n0,
                                      bf* lsA, bf* lsB, const bf* zpg) {
  const int t = threadIdx.x;
  const bf* Ap = g.A + (long)(z >> g.zshA) * g.sAz;
  const bf* Bp = g.B + (long)(z & g.zmskB) * g.sBz;
  const int w = t >> 6, l = t & 63;
  const int wm = (w >> 1) * 64, wn = (w & 1) * 64;
  const int lr = l & 15, lk = (l >> 4) * 8;
  const int r0 = t >> 2, ko = (t & 3) * 8;
  const long rowA1 = m0 + r0, rowA2 = rowA1 + 64;
  const long baseA1 = (rowA1 >> 9) * g.lMa + (rowA1 & 511) * g.la;
  const long baseA2 = (rowA2 >> 9) * g.lMa + (rowA2 & 511) * g.la;
  const long baseB1 = (n0 + r0) * g.lb;
  const int zbA = z * g.kzA, zbB = z * g.kzB;
  const int ct = ((int)rowA1 + 1) & 7;
  const long convB = (long)ct * 2065 + 1023 - (long)rowA1;
  const int Kend = (tMASK == 3) ? ((g.K < (int)m0 + 128) ? g.K : (int)m0 + 128) : g.K;
  f32x4 acc[4][4];
  #pragma unroll
  for (int i = 0; i < 4; i++)
    #pragma unroll
    for (int j = 0; j < 4; j++) acc[i][j] = (f32x4){0.f, 0.f, 0.f, 0.f};

  for (int k0 = 0; k0 < Kend; k0 += 32) {
    const int kk = k0 + ko;
    const int bA = (kk >> 9) + zbA, bB = (kk >> 9) + zbB;
    const long kb = (long)bB * g.lKb + (kk & 511);
    const bf* ga; const bf* ga2;
    if (tMASK == 3) {
      ga  = Ap + convB + kk;
      ga2 = ga - 64;
    } else {
      const long ka = (long)bA * g.lKa + (kk & 511);
      ga  = Ap + baseA1 + ka;
      ga2 = Ap + baseA2 + ka;
      if (tMASK == 1) { if ((int)(rowA1 & 15) < bA) { ga = zpg; ga2 = zpg; } }
      if (tMASK == 2) { if ((int)(rowA1 & 63) < g.maskCmp) { ga = zpg; ga2 = zpg; } }
    }
    const bf* gb = Bp + baseB1 + kb;
    gload16(ga,             &lsA[t * 8]);
    gload16(ga2,            &lsA[2048 + t * 8]);
    gload16(gb,             &lsB[t * 8]);
    gload16(gb + 64 * g.lb, &lsB[2048 + t * 8]);
    __syncthreads();
    bfv8 av[4], bv[4];
    #pragma unroll
    for (int i = 0; i < 4; i++) av[i] = *(const bfv8*)&lsA[(wm + i * 16 + lr) * 32 + lk];
    #pragma unroll
    for (int i = 0; i < 4; i++) bv[i] = *(const bfv8*)&lsB[(wn + i * 16 + lr) * 32 + lk];
    #pragma unroll
    for (int i = 0; i < 4; i++)
      #pragma unroll
      for (int j = 0; j < 4; j++)
        acc[i][j] = __builtin_amdgcn_mfma_f32_16x16x32_bf16(av[i], bv[j], acc[i][j], 0, 0, 0);
    __syncthreads();
  }
  const int orow = (l >> 4) * 4, ocol = lr;
  #pragma unroll
  for (int i = 0; i < 4; i++)
    #pragma unroll
    for (int j = 0; j < 4; j++) {
      long col = n0 + wn + j * 16 + ocol;
      float bb = tB ? g.bias[col] : 0.f;
      #pragma unroll
      for (int r = 0; r < 4; r++) {
        long row = m0 + wm + i * 16 + orow + r;
        float v = acc[i][j][r] + bb;
        if (tF32) {
          long idx = (long)z * g.sCz + row * g.ldc + col;
          if (tACC) v += g.C[idx];
          g.C[idx] = v;
        }
        if (tB16) {
          if (tSHW) {
            if ((row & 63) != 63)
              g.Cb[(long)z * g.sCbz + (row + 1) * g.ldcb + col] = (bf)v;
          } else {
            g.Cb[(long)z * g.sCbz + row * g.ldcb + col] = (bf)v;
          }
        }
      }
    }
}

// merged kernel: z < Zmain -> main op (tPAIR: also mirrored m-tile 2*gridDim.x-1-x);
// z >= Zmain -> special tiles. Special flat id: flat < 32*gx.spS -> op gx,
// matrix zz=flat>>5 (M=512: 4x8 tiles); else op gy (M=1024: 8x8 tiles).
template<int tB,int tF32,int tB16,int tMASK,int tACC,int tPAIR=0,int tSPEC=0,
         int sB=0,int sF32=0,int sB16=0,int sMASK=0,int sACC=0,int tSHW=0>
__global__ __launch_bounds__(256) void gemm_k(GOp g, GOp gx, GOp gy, int Zmain,
                                              const bf* __restrict__ zpg) {
  __shared__ bf lsA[4096], lsB[4096];
  int z = blockIdx.z;
  if (tSPEC && z >= Zmain) {
    int flat = (z - Zmain) * (int)(gridDim.x * gridDim.y)
             + (int)blockIdx.y * (int)gridDim.x + (int)blockIdx.x;
    if (flat >= gx.mBlk) return;
    int dxT = gx.spS * 32;
    if (flat < dxT) {
      int zz = flat >> 5, t32 = flat & 31;
      gbody<sB,sF32,sB16,sMASK,sACC>(gx, zz, (long)(t32 >> 3) * 128, (long)(t32 & 7) * 128,
                                     lsA, lsB, zpg);
    } else {
      int f = flat - dxT;
      gbody<sB,sF32,sB16,sMASK,sACC>(gy, 0, (long)(f >> 3) * 128, (long)(f & 7) * 128,
                                     lsA, lsB, zpg);
    }
  } else {
    gbody<tB,tF32,tB16,tMASK,tACC,tSHW>(g, z, (long)blockIdx.x * 128, (long)blockIdx.y * 128,
                                        lsA, lsB, zpg);
    if (tPAIR)
      gbody<tB,tF32,tB16,tMASK,tACC,tSHW>(g, z, (long)(2 * gridDim.x - 1 - blockIdx.x) * 128,
                                          (long)blockIdx.y * 128, lsA, lsB, zpg);
  }
}

static inline GOp mkop(const void* A, long la, long lKa, long lMa, long sAz, int zshA, int kzA,
                       const void* B, long lb, long lKb, long sBz, int zmskB, int kzB,
                       void* C, long ldc, long sCz, void* Cb, long ldcb, long sCbz,
                       const void* bias, int K) {
  GOp g;
  g.A = (const bf*)A; g.la = la; g.lKa = lKa; g.lMa = lMa; g.sAz = sAz; g.zshA = zshA; g.kzA = kzA;
  g.B = (const bf*)B; g.lb = lb; g.lKb = lKb; g.sBz = sBz; g.zmskB = zmskB; g.kzB = kzB;
  g.C = (float*)C; g.ldc = ldc; g.sCz = sCz;
  g.Cb = (bf*)Cb; g.ldcb = ldcb; g.sCbz = sCbz;
  g.bias = (const float*)bias; g.K = K; g.maskCmp = 0; g.mBlk = 0; g.spS = 0;
  return g;
}

template<int tB,int tF32,int tB16,int tMASK,int tACC,int tPAIR=0,int tSPEC=0,
         int sB=0,int sF32=0,int sB16=0,int sMASK=0,int sACC=0,int tSHW=0>
static inline void LG(hipStream_t st, int gx_, int gy_, int gz_, const GOp& g,
                      const GOp& gsx, const GOp& gsy, int Zmain, const bf* zpg) {
  gemm_k<tB,tF32,tB16,tMASK,tACC,tPAIR,tSPEC,sB,sF32,sB16,sMASK,sACC,tSHW>
      <<<dim3(gx_, gy_, gz_), 256, 0, st>>>(g, gsx, gsy, Zmain, zpg);
}

// ---------------- small kernels ----------------

template<typename TI, typename TO>
__global__ __launch_bounds__(256) void k_trt(const TI* __restrict__ in, TO* __restrict__ out,
                                             long ldin, long inz, long ldout, long outz) {
  __shared__ float tile[64][65];
  int z = blockIdx.z;
  int c0 = blockIdx.x * 64, r0 = blockIdx.y * 64;
  int tx = threadIdx.x & 63, ty = threadIdx.x >> 6;
  #pragma unroll
  for (int i = ty; i < 64; i += 4) tile[i][tx] = (float)in[(long)z * inz + (long)(c0 + i) * ldin + r0 + tx];
  __syncthreads();
  #pragma unroll
  for (int i = ty; i < 64; i += 4) out[(long)z * outz + (long)(r0 + i) * ldout + c0 + tx] = (TO)tile[tx][i];
}

__global__ __launch_bounds__(256) void k_trtS(const float* __restrict__ in, bf* __restrict__ out,
                                              long ldin, long ldout, const float* __restrict__ scl) {
  __shared__ float tile[64][65];
  int c0 = blockIdx.x * 64, r0 = blockIdx.y * 64;
  int tx = threadIdx.x & 63, ty = threadIdx.x >> 6;
  #pragma unroll
  for (int i = ty; i < 64; i += 4) tile[i][tx] = in[(long)(c0 + i) * ldin + r0 + tx];
  __syncthreads();
  float sc = scl[(c0 + tx) >> 9];
  #pragma unroll
  for (int i = ty; i < 64; i += 4) out[(long)(r0 + i) * ldout + c0 + tx] = (bf)(tile[tx][i] * sc);
}

__global__ void k_scl(const float* __restrict__ evals, float* __restrict__ scl) {
  int k = threadIdx.x;
  if (k < 24) scl[k] = powf(evals[k], 0.25f);
}

__global__ void k_pvec(const float* __restrict__ evecs, bf* __restrict__ out) {
  long id = (long)blockIdx.x * 256 + threadIdx.x;
  if (id >= 24L * 16512) return;
  int kf = (int)(id / 16512);
  int rem = (int)(id % 16512);
  int c = rem / 2064, j = rem % 2064;
  int d = j - c;
  float v = (d >= 0 && d <= 1023) ? evecs[(long)(1023 - d) * 24 + kf] : 0.f;
  out[id] = (bf)v;
}

__global__ void k_mut(const float* __restrict__ mul_, bf* __restrict__ out) {
  long id = (long)blockIdx.x * 256 + threadIdx.x;  // < 786432
  long r = id >> 9; int d = (int)(id & 511);
  int i = (int)(r >> 9), o = (int)(r & 511);
  out[id] = (bf)mul_[(long)o * 1536 + d * 3 + i];
}

// PT layout init: PT[1] = [A|B] = myl (at block 15), PT[0] = [I|0] (block 16),
// TRSa = (CM^1)^T = [myl^T | [I;0]]
__global__ __launch_bounds__(256) void k_prep(const float* __restrict__ myl,
                                              bf* __restrict__ ptop, bf* __restrict__ trs) {
  __shared__ float t[64][65];
  long bid = blockIdx.x;
  if (bid < 768) {
    long id = bid * 2048 + (long)threadIdx.x * 8;
    #pragma unroll
    for (int u = 0; u < 8; ++u) {
      long i = id + u;
      if (i < 524288) {                      // PT[1] = myl
        ptop[15L * 524288 + i] = (bf)myl[i];
      } else if (i < 1048576) {              // PT[0] = [I | 0]
        long i2 = i - 524288;
        int p = (int)(i2 >> 10), q = (int)(i2 & 1023);
        ptop[16L * 524288 + i2] = (bf)((q == p) ? 1.f : 0.f);
      } else {                               // TRS right half [1024][512..]
        long i3 = i - 1048576;
        int x = (int)(i3 >> 9), y = (int)(i3 & 511);
        trs[(long)x * 1024 + 512 + y] = (bf)((x == y) ? 1.f : 0.f);
      }
    }
  } else {
    int tile = (int)(bid - 768);             // 128 tiles: TRS left = myl^T
    int txx = tile >> 3, tyy = tile & 7;
    int lx = threadIdx.x & 63, ly = threadIdx.x >> 6;
    #pragma unroll
    for (int i = ly; i < 64; i += 4)
      t[i][lx] = myl[(long)(tyy * 64 + i) * 1024 + txx * 64 + lx];
    __syncthreads();
    #pragma unroll
    for (int i = ly; i < 64; i += 4)
      trs[(long)(txx * 64 + i) * 1024 + tyy * 64 + lx] = (bf)t[lx][i];
  }
}

__global__ __launch_bounds__(256) void k_ln(const float* __restrict__ x, const float* __restrict__ sc,
                                            const float* __restrict__ bi, bf* __restrict__ hb) {
  __shared__ float red[8];
  long row = blockIdx.x;
  const float* xr = x + row * 512;
  int t = threadIdx.x;
  float a = xr[t], b2 = xr[t + 256];
  float s = a + b2;
  #pragma unroll
  for (int o = 32; o; o >>= 1) s += __shfl_down(s, o, 64);
  if ((t & 63) == 0) red[t >> 6] = s;
  __syncthreads();
  float mu = (red[0] + red[1] + red[2] + red[3]) * (1.f / 512.f);
  __syncthreads();
  float c1 = a - mu, c2 = b2 - mu;
  float qq = c1 * c1 + c2 * c2;
  #pragma unroll
  for (int o = 32; o; o >>= 1) qq += __shfl_down(qq, o, 64);
  if ((t & 63) == 0) red[t >> 6] = qq;
  __syncthreads();
  float var = (red[0] + red[1] + red[2] + red[3]) * (1.f / 512.f);
  float rs = rsqrtf(var + 1e-5f);
  hb[row * 512 + t]       = (bf)(c1 * rs * sc[t] + bi[t]);
  hb[row * 512 + t + 256] = (bf)(c2 * rs * sc[t + 256] + bi[t + 256]);
}

__global__ void k_deltasS(const float* __restrict__ dp, long stride, int S,
                          const bf* __restrict__ callb, bf* __restrict__ db) {
  long id = (long)blockIdx.x * 256 + threadIdx.x;  // < 2097152
  int o = (int)(id & 511); long row = id >> 9; int tt = (int)(row & 1023);
  float v = 0.f;
  for (int zz = 0; zz < S; ++zz) v += dp[(long)zz * stride + id];
  for (int i = 0; i < 3; ++i)
    if (tt >= i) v += (float)callb[(row - i) * 1536 + i * 512 + o];
  db[id] = (bf)v;
}

__global__ void k_egather(const float* __restrict__ dp, long stride, int S,
                          float* __restrict__ E, bf* __restrict__ eb0) {
  long id = (long)blockIdx.x * 256 + threadIdx.x;  // < 262144
  int p = (int)(id & 1023); long r = id >> 10;
  int b = (int)(r >> 6), c = (int)(r & 63);
  int tq = c * 16 + ((p < 512) ? 15 : 14);
  long idx = ((long)(b << 10) + tq) * 512 + (p & 511);
  float v = 0.f;
  for (int zz = 0; zz < S; ++zz) v += dp[(long)zz * stride + idx];
  E[id] = v; eb0[id] = (bf)v;
}

__global__ void k_combgelu(const float* __restrict__ dp, long stride, int S,
                           const bf* __restrict__ outh, bf* __restrict__ yg) {
  long id = (long)blockIdx.x * 256 + threadIdx.x;  // < 2097152
  int o = (int)(id & 511); long row = id >> 9;
  int b = (int)(row >> 10), tt = (int)(row & 1023);
  int c = tt >> 4, j = tt & 15;
  long wv = ((long)(j * 512 + o)) * 256 + b * 64 + c;
  float v = (float)outh[wv];
  for (int zz = 0; zz < S; ++zz) v += dp[(long)zz * stride + id];
  yg[id] = (bf)(0.5f * v * (1.f + erff(v * 0.70710678118654752f)));
}

__global__ void k_glures(const bf* __restrict__ g, float* __restrict__ x) {
  long id = (long)blockIdx.x * 256 + threadIdx.x;  // < 2097152
  int o = (int)(id & 511); long row = id >> 9;
  float a = (float)g[row * 1024 + o], bb = (float)g[row * 1024 + 512 + o];
  x[id] = x[id] + a / (1.f + expf(-bb));
}

__global__ void k_cast(const float* __restrict__ in, bf* __restrict__ out, long n4) {
  long id = (long)blockIdx.x * 256 + threadIdx.x;
  if (id >= n4) return;
  float4 v = *(const float4*)(in + id * 4);
  bfv4 o; o[0] = (bf)v.x; o[1] = (bf)v.y; o[2] = (bf)v.z; o[3] = (bf)v.w;
  *(bfv4*)(out + id * 4) = o;
}

__global__ void k_fill(float* p, long n, float v) {
  long id = (long)blockIdx.x * 256 + threadIdx.x;
  if (id < n) p[id] = v;
}

// ---------------- workspace layout (byte offsets) ----------------
struct Lay {
  long ZPG, SSTB, SCL, EMBT, PROJT, PVEC, PTOP, TRS, WU, X, MPHITL, MUTL, W1TL,
       HB, HTB, DSLOT, DP, RC, E, EB0, EB1, need;
  int nk, S;
};
static Lay mkLay(int nk, int S) {
  Lay L; long o = 0;
  auto al = [&](long sz) { long r = o; o += (sz + 255) & ~255L; return r; };
  L.nk = nk; L.S = S;
  L.ZPG   = al(4096);
  L.SSTB  = al(524288);
  L.SCL   = al(256);
  L.EMBT  = al(524288);
  L.PROJT = al(524288);
  L.PVEC  = al(24L * 16512 * 2);
  L.PTOP  = al(17L * 1048576);           // PT[i] tops, descending powers
  L.TRS   = al(2L * 2097152);            // TRSa | TRSb
  L.WU    = al(8388608);                 // WUa(W,U) | WUb(W,U)
  L.X     = al(8388608);
  L.MPHITL= al(12582912);
  L.MUTL  = al(1572864);
  L.W1TL  = al(1048576);
  L.HB    = al(4194304);
  L.HTB   = al(4194304);
  L.DSLOT = al(4194304);                 // DELTAB | YGB
  L.DP    = al((long)S * 8388608);
  long rc = (long)nk * 4194304;          // XTC
  if (rc < 16777216) rc = 16777216;      // CALLB + OUTH ; G
  L.RC    = al(rc);
  L.E     = al(1048576);
  L.EB0   = al(524288);
  L.EB1   = al(524288);
  L.need  = o;
  return L;
}

extern "C" void kernel_launch(void* const* d_in, const int* in_sizes, int n_in,
                              void* d_out, int out_size, void* d_ws, size_t ws_size,
                              hipStream_t stream) {
  Lay L = mkLay(12, 4);                        // ~155 MB (proven fit)
  if (L.need > (long)ws_size) L = mkLay(8, 4); // ~138 MB
  if (L.need > (long)ws_size) L = mkLay(4, 2); // ~104 MB
  if (L.need > (long)ws_size) {
    k_fill<<<8192, 256, 0, stream>>>((float*)d_out, 2097152, 1.0e6f + (float)(ws_size >> 20));
    return;
  }
  const float* inp  = (const float*)d_in[0];
  const float* embw = (const float*)d_in[1];
  const float* embb = (const float*)d_in[2];
  const float* lns  = (const float*)d_in[3];
  const float* lnb  = (const float*)d_in[4];
  const float* m_y  = (const float*)d_in[5];
  const float* m_u  = (const float*)d_in[6];
  const float* mphi = (const float*)d_in[7];
  const float* w1   = (const float*)d_in[8];
  const float* b1   = (const float*)d_in[9];
  const float* pw   = (const float*)d_in[10];
  const float* pb   = (const float*)d_in[11];
  const float* evals = (const float*)d_in[12];
  const float* evecs = (const float*)d_in[13];

  char* w = (char*)d_ws;
  bf*    ZPG   = (bf*)(w + L.ZPG);
  bf*    SSTB  = (bf*)(w + L.SSTB);
  float* SCL   = (float*)(w + L.SCL);
  bf*    EMBT  = (bf*)(w + L.EMBT);
  bf*    PROJT = (bf*)(w + L.PROJT);
  bf*    PVEC  = (bf*)(w + L.PVEC);
  bf*    PTOP  = (bf*)(w + L.PTOP);      // PT(i) = PTOP + (16-i)*524288
  bf*    TRSa  = (bf*)(w + L.TRS);
  bf*    TRSb  = TRSa + 1048576;
  bf*    WUa   = (bf*)(w + L.WU);
  bf*    WUb   = (bf*)(w + L.WU + 4194304);
  float* X     = (float*)(w + L.X);
  bf*    MPHITL= (bf*)(w + L.MPHITL);
  bf*    MUTL  = (bf*)(w + L.MUTL);
  bf*    W1TL  = (bf*)(w + L.W1TL);
  bf*    HB    = (bf*)(w + L.HB);
  bf*    HTB   = (bf*)(w + L.HTB);
  bf*    DELTAB= (bf*)(w + L.DSLOT);
  bf*    YGB   = (bf*)(w + L.DSLOT);
  float* DP    = (float*)(w + L.DP);
  bf*    XTC   = (bf*)(w + L.RC);
  bf*    CALLB = (bf*)(w + L.RC);
  bf*    OUTH  = (bf*)(w + L.RC + 12582912);
  bf*    G     = (bf*)(w + L.RC);
  float* E     = (float*)(w + L.E);
  bf*    EB0   = (bf*)(w + L.EB0);
  bf*    EB1   = (bf*)(w + L.EB1);
  bf*    INB   = HB;
  hipStream_t st = stream;
  const int nk = L.nk, S = L.S, nchunk = 24 / nk;
  const long DPS = 2097152;
  const int Kcphi = nk * 512 / S, kzphi = Kcphi >> 9;
  const int Kcy = 8192 / S, kzy = Kcy >> 9;
  GOp gnull = {};
  const int BIGZ = 1 << 30;

  hipMemsetAsync(w + L.ZPG, 0, 4096, st);
  for (int b = 0; b < 4; ++b)                    // SSTB c=0 rows stay zero
    hipMemsetAsync(w + L.SSTB + (long)b * 64 * 2048, 0, 2048, st);

  // ---- one-time prep ----
  k_scl<<<1, 32, 0, st>>>(evals, SCL);
  k_pvec<<<1549, 256, 0, st>>>(evecs, PVEC);
  k_trt<float, bf><<<dim3(8, 8, 1), 256, 0, st>>>(embw, EMBT, 512, 0, 512, 0);
  k_trt<float, bf><<<dim3(8, 8, 1), 256, 0, st>>>(pw, PROJT, 512, 0, 512, 0);
  k_cast<<<2048, 256, 0, st>>>(inp, INB, 524288);
  LG<1,1,0,0,0>(st, 32, 4, 1,
      mkop(INB, 512, 512, 262144, 0, 30, 0, EMBT, 512, 512, 0, 0, 0,
           X, 512, 0, nullptr, 0, 0, embb, 512), gnull, gnull, BIGZ, ZPG);

  for (int l = 0; l < 4; ++l) {
    // --- PT init + (CM^1)^T ---
    k_prep<<<896, 256, 0, st>>>(m_y + (long)l * 524288, PTOP, TRSa);
    // --- per-layer weight prep ---
    k_trtS<<<dim3(192, 8, 1), 256, 0, st>>>(mphi + (long)l * 6291456, MPHITL, 512, 12288, SCL);
    k_mut<<<3072, 256, 0, st>>>(m_u + (long)l * 786432, MUTL);
    k_trt<float, bf><<<dim3(8, 16, 1), 256, 0, st>>>(w1 + (long)l * 524288, W1TL, 1024, 0, 512, 0);

    // --- LN -> HB ; HTB per-batch transpose ---
    k_ln<<<4096, 256, 0, st>>>(X, lns + l * 512, lnb + l * 512, HB);
    k_trt<bf, bf><<<dim3(16, 8, 4), 256, 0, st>>>(HB, HTB, 512, 524288, 1024, 524288);

    // --- spectral conv (paired m-tiles) + phi; doubling rides r=0..3 ---
    int hostRound = 0;
    auto mkDXY = [&](int s, bf* TRScur, bf* TRSnxt, GOp& dx, GOp& dy) {
      dx = mkop(PTOP + 15L * 524288, 1024, 512, 0, -524288L, 0, 0,
                TRScur, 1024, 512, 0, 0, 0,
                nullptr, 0, 0, PTOP + (long)(15 - s) * 524288, 1024, -524288L,
                nullptr, 1024);
      dx.mBlk = 32 * s + 64; dx.spS = s;
      dy = mkop(TRScur, 1024, 512, 524288, 0, 0, 0,
                PTOP + (long)(16 - s) * 524288, 1024, 512, 0, 0, 0,
                nullptr, 0, 0, TRSnxt, 1024, 0, nullptr, 1024);
    };
    for (int kc = 0; kc < nchunk; ++kc) {
      GOp gconv = mkop(PVEC + (long)kc * nk * 16512, 0, 0, 0, 16512, 2, 0,
                       HTB, 1024, 512, 524288, 3, 0,
                       nullptr, 0, 0, XTC, 512, 524288, nullptr, 1024);
      if (hostRound < 4) {
        int s = 1 << hostRound;
        bf* TRScur = (hostRound & 1) ? TRSb : TRSa;
        bf* TRSnxt = (hostRound & 1) ? TRSa : TRSb;
        GOp dx, dy; mkDXY(s, TRScur, TRSnxt, dx, dy);
        int nzs = (dx.mBlk + 15) / 16;            // 4x4 tiles per ride z
        LG<0,0,1,3,0, 1,1, 0,0,1,0,0>(st, 4, 4, 4 * nk + nzs, gconv, dx, dy, 4 * nk, ZPG);
        ++hostRound;
      } else {
        LG<0,0,1,3,0, 1,0>(st, 4, 4, 4 * nk, gconv, gnull, gnull, BIGZ, ZPG);
      }
      GOp gphi = mkop(XTC, 512, 2097152, 262144, 0, 30, kzphi,
                      MPHITL + (long)kc * nk * 512, 12288, 512, 0, 0, kzphi,
                      DP, 512, DPS, nullptr, 0, 0, nullptr, Kcphi);
      if (hostRound < 4) {
        int s = 1 << hostRound;
        bf* TRScur = (hostRound & 1) ? TRSb : TRSa;
        bf* TRSnxt = (hostRound & 1) ? TRSa : TRSb;
        GOp dx, dy; mkDXY(s, TRScur, TRSnxt, dx, dy);
        int nzs = (dx.mBlk + 127) / 128;
        if (kc == 0) LG<0,1,0,0,0, 0,1, 0,0,1,0,0>(st, 32, 4, S + nzs, gphi, dx, dy, S, ZPG);
        else         LG<0,1,0,0,1, 0,1, 0,0,1,0,0>(st, 32, 4, S + nzs, gphi, dx, dy, S, ZPG);
        ++hostRound;
      } else {
        if (kc == 0) LG<0,1,0,0,0>(st, 32, 4, S, gphi, gnull, gnull, BIGZ, ZPG);
        else         LG<0,1,0,0,1>(st, 32, 4, S, gphi, gnull, gnull, BIGZ, ZPG);
      }
    }

    // --- AR terms (+ rides W2/U2 squaring: WUa = W^2 | U^2 from W1=PTOP,U1=TRSa) ---
    {
      GOp gcall = mkop(HB, 512, 512, 262144, 0, 30, 0, MUTL, 512, 512, 0, 0, 0,
                       nullptr, 0, 0, CALLB, 1536, 0, nullptr, 512);
      GOp w2x = mkop(PTOP, 1024, 512, 0, 524288, 0, 0,
                     TRSa, 1024, 512, 0, 0, 0,
                     nullptr, 0, 0, WUa, 1024, 524288, nullptr, 1024);
      w2x.mBlk = 128; w2x.spS = 2;
      GOp u2y = mkop(TRSa, 1024, 512, 524288, 0, 0, 0,
                     PTOP, 1024, 512, 0, 0, 0,
                     nullptr, 0, 0, WUa + 1048576, 1024, 0, nullptr, 1024);
      LG<0,0,1,0,0, 0,1, 0,0,1,0,0>(st, 32, 12, 2, gcall, w2x, u2y, 1, ZPG);
    }
    k_deltasS<<<8192, 256, 0, st>>>(DP, DPS, S, CALLB, DELTAB);

    // --- local solutions (+ rides W4/U4 squaring from WUa -> WUb) ---
    {
      GOp gyloc = mkop(DELTAB, 512, -512, 262144, 0, 30, kzy,
                       PTOP + 16L * 524288, 1024, -524288L, 0, 0, kzy,
                       DP, 512, DPS, nullptr, 0, 0, nullptr, Kcy);
      GOp w4x = mkop(WUa, 1024, 512, 0, 524288, 0, 0,
                     WUa + 1048576, 1024, 512, 0, 0, 0,
                     nullptr, 0, 0, WUb, 1024, 524288, nullptr, 1024);
      w4x.mBlk = 128; w4x.spS = 2;
      GOp u4y = mkop(WUa + 1048576, 1024, 512, 524288, 0, 0, 0,
                     WUa, 1024, 512, 0, 0, 0,
                     nullptr, 0, 0, WUb + 1048576, 1024, 0, nullptr, 1024);
      LG<0,1,0,1,0, 0,1, 0,0,1,0,0>(st, 32, 4, S + 1, gyloc, w4x, u4y, S, ZPG);
    }

    // --- Kogge-Stone scan ---
    k_egather<<<1024, 256, 0, st>>>(DP, DPS, S, E, EB0);
    // L1: E1 (W1=PTOP, sh=1): EB0 -> EB1
    {
      GOp e1 = mkop(EB0 - 1024, 1024, 512, 524288, 0, 30, 0,
                    PTOP, 1024, 512, 0, 0, 0,
                    E, 1024, 0, EB1, 1024, 0, nullptr, 1024);
      e1.maskCmp = 1;
      LG<0,1,1,2,1>(st, 2, 8, 1, e1, gnull, gnull, BIGZ, ZPG);
    }
    // L2: E2 (W2=WUa, sh=2): EB1 -> EB0
    {
      GOp e2 = mkop(EB1 - 2048, 1024, 512, 524288, 0, 30, 0,
                    WUa, 1024, 512, 0, 0, 0,
                    E, 1024, 0, EB0, 1024, 0, nullptr, 1024);
      e2.maskCmp = 2;
      LG<0,1,1,2,1>(st, 2, 8, 1, e2, gnull, gnull, BIGZ, ZPG);
    }
    // L3: {W8/U8 from WUb} || E3 (W4=WUb, sh=4): EB0 -> EB1 ; out WUa
    {
      GOp mn8 = mkop(WUb, 1024, 512, 524288, 1048576, 0, 0,
                     WUb + 1048576, 1024, 512, -1048576, 1, 0,
                     nullptr, 0, 0, WUa, 1024, 1048576, nullptr, 1024);
      GOp sp3 = mkop(EB0 - 4096, 1024, 512, 524288, 0, 30, 0,
                     WUb, 1024, 512, 0, 0, 0,
                     E, 1024, 0, EB1, 1024, 0, nullptr, 1024);
      sp3.maskCmp = 4; sp3.mBlk = 16; sp3.spS = 99;
      LG<0,0,1,0,0, 0,1, 0,1,1,2,1>(st, 8, 8, 3, mn8, sp3, gnull, 2, ZPG);
    }
    // L4: {W16/U16 from WUa} || E4 (W8=WUa, sh=8): EB1 -> EB0 ; out WUb
    {
      GOp mn16 = mkop(WUa, 1024, 512, 524288, 1048576, 0, 0,
                      WUa + 1048576, 1024, 512, -1048576, 1, 0,
                      nullptr, 0, 0, WUb, 1024, 1048576, nullptr, 1024);
      GOp sp4 = mkop(EB1 - 8192, 1024, 512, 524288, 0, 30, 0,
                     WUa, 1024, 512, 0, 0, 0,
                     E, 1024, 0, EB0, 1024, 0, nullptr, 1024);
      sp4.maskCmp = 8; sp4.mBlk = 16; sp4.spS = 99;
      LG<0,0,1,0,0, 0,1, 0,1,1,2,1>(st, 8, 8, 3, mn16, sp4, gnull, 2, ZPG);
    }
    // L5: {W32 only from WUb} || E5 (W16=WUb, sh=16): EB0 -> EB1 ; out WUa(z=0)
    {
      GOp mn32 = mkop(WUb, 1024, 512, 524288, 1048576, 0, 0,
                      WUb + 1048576, 1024, 512, -1048576, 1, 0,
                      nullptr, 0, 0, WUa, 1024, 1048576, nullptr, 1024);
      GOp sp5 = mkop(EB0 - 16384, 1024, 512, 524288, 0, 30, 0,
                     WUb, 1024, 512, 0, 0, 0,
                     E, 1024, 0, EB1, 1024, 0, nullptr, 1024);
      sp5.maskCmp = 16; sp5.mBlk = 16; sp5.spS = 99;
      LG<0,0,1,0,0, 0,1, 0,1,1,2,1>(st, 8, 8, 2, mn32, sp5, gnull, 1, ZPG);
    }
    // fe: E6 (W32=WUa, sh=32): EB1 -> SSTB (shifted bf16) + E
    {
      GOp fe = mkop(EB1 - 32768, 1024, 512, 524288, 0, 30, 0,
                    WUa, 1024, 512, 0, 0, 0,
                    E, 1024, 0, SSTB, 1024, 0, nullptr, 1024);
      fe.maskCmp = 32;
      LG<0,1,1,2,1, 0,0, 0,0,0,0,0, 1>(st, 2, 8, 1, fe, gnull, gnull, BIGZ, ZPG);
    }

    // --- homogeneous completion (A = PT tops, desc) + gelu + MLP(GLU) ---
    LG<0,0,1,0,0>(st, 64, 2, 1,
        mkop(PTOP + 15L * 524288, 1024, 512, -524288L, 0, 30, 0,
             SSTB, 1024, 512, 0, 0, 0,
             nullptr, 0, 0, OUTH, 256, 0, nullptr, 1024), gnull, gnull, BIGZ, ZPG);
    k_combgelu<<<8192, 256, 0, st>>>(DP, DPS, S, OUTH, YGB);
    LG<1,0,1,0,0>(st, 32, 8, 1,
        mkop(YGB, 512, 512, 262144, 0, 30, 0, W1TL, 512, 512, 0, 0, 0,
             nullptr, 0, 0, G, 1024, 0, b1 + (long)l * 1024, 512), gnull, gnull, BIGZ, ZPG);
    k_glures<<<8192, 256, 0, st>>>(G, X);
  }

  // ---- output projection ----
  k_cast<<<2048, 256, 0, st>>>(X, INB, 524288);
  LG<1,1,0,0,0>(st, 32, 4, 1,
      mkop(INB, 512, 512, 262144, 0, 30, 0, PROJT, 512, 512, 0, 0, 0,
           (float*)d_out, 512, 0, nullptr, 0, 0, pb, 512), gnull, gnull, BIGZ, ZPG);
}

// Round 15
// 2639.279 us; speedup vs baseline: 1.0181x; 1.0181x over previous
//
#include <hip/hip_runtime.h>
#include <math.h>

typedef __bf16 bf;
typedef __attribute__((ext_vector_type(4))) __bf16 bfv4;
typedef __attribute__((ext_vector_type(8))) __bf16 bfv8;
typedef __attribute__((ext_vector_type(4))) float f32x4;

__device__ __forceinline__ void gload16(const void* g, void* l) {
  __builtin_amdgcn_global_load_lds((const __attribute__((address_space(1))) void*)g,
                                   (__attribute__((address_space(3))) void*)l, 16, 0, 0);
}

// ---------------- generalized GEMM op descriptor ----------------
// C[M,N] = A[M,K] * Bt[N,K]^T, bf16 in, f32 accum, 128x128 tile, BK=32.
// A row addr: (row>>9)*lMa + (row&511)*la ; K addr: blk*lK + (k&511),
// blk = (k>>9) + z*kz. Z: A += (z>>zshA)*sAz, B += (z&zmskB)*sBz, C += z*sCz.
// tMASK=1: causal im2col (valid iff (row&15) >= blk), zero-page redirect.
// tMASK=2: scan shift (valid iff (row&63) >= maskCmp), zero-page redirect.
// tMASK=3: Toeplitz conv: A elem(row=t, k=s) = pvec[c*2065 + 1023 - t + s],
//          c=(t+1)&7; causal => per-tile K clamp to m0+128.
struct GOp {
  const bf* A; long la, lKa, lMa, sAz; int zshA, kzA;
  const bf* B; long lb, lKb, sBz; int zmskB, kzB;
  float* C; long ldc, sCz;
  bf* Cb; long ldcb, sCbz;
  const float* bias; int K, maskCmp, mBlk, spS;
};

template<int tB,int tF32,int tB16,int tMASK,int tACC>
__device__ __forceinline__ void gbody(const GOp g, int z, long m0, long n0,
                                      bf* lsA, bf* lsB, const bf* zpg) {
  const int t = threadIdx.x;
  const bf* Ap = g.A + (long)(z >> g.zshA) * g.sAz;
  const bf* Bp = g.B + (long)(z & g.zmskB) * g.sBz;
  const int w = t >> 6, l = t & 63;
  const int wm = (w >> 1) * 64, wn = (w & 1) * 64;
  const int lr = l & 15, lk = (l >> 4) * 8;
  const int r0 = t >> 2, ko = (t & 3) * 8;
  const long rowA1 = m0 + r0, rowA2 = rowA1 + 64;
  const long baseA1 = (rowA1 >> 9) * g.lMa + (rowA1 & 511) * g.la;
  const long baseA2 = (rowA2 >> 9) * g.lMa + (rowA2 & 511) * g.la;
  const long baseB1 = (n0 + r0) * g.lb;
  const int zbA = z * g.kzA, zbB = z * g.kzB;
  const int ct = ((int)rowA1 + 1) & 7;
  const long convB = (long)ct * 2065 + 1023 - (long)rowA1;
  const int Kend = (tMASK == 3) ? ((g.K < (int)m0 + 128) ? g.K : (int)m0 + 128) : g.K;
  f32x4 acc[4][4];
  #pragma unroll
  for (int i = 0; i < 4; i++)
    #pragma unroll
    for (int j = 0; j < 4; j++) acc[i][j] = (f32x4){0.f, 0.f, 0.f, 0.f};

  for (int k0 = 0; k0 < Kend; k0 += 32) {
    const int kk = k0 + ko;
    const int bA = (kk >> 9) + zbA, bB = (kk >> 9) + zbB;
    const long kb = (long)bB * g.lKb + (kk & 511);
    const bf* ga; const bf* ga2;
    if (tMASK == 3) {
      ga  = Ap + convB + kk;
      ga2 = ga - 64;
    } else {
      const long ka = (long)bA * g.lKa + (kk & 511);
      ga  = Ap + baseA1 + ka;
      ga2 = Ap + baseA2 + ka;
      if (tMASK == 1) { if ((int)(rowA1 & 15) < bA) { ga = zpg; ga2 = zpg; } }
      if (tMASK == 2) { if ((int)(rowA1 & 63) < g.maskCmp) { ga = zpg; ga2 = zpg; } }
    }
    const bf* gb = Bp + baseB1 + kb;
    gload16(ga,             &lsA[t * 8]);
    gload16(ga2,            &lsA[2048 + t * 8]);
    gload16(gb,             &lsB[t * 8]);
    gload16(gb + 64 * g.lb, &lsB[2048 + t * 8]);
    __syncthreads();
    bfv8 av[4], bv[4];
    #pragma unroll
    for (int i = 0; i < 4; i++) av[i] = *(const bfv8*)&lsA[(wm + i * 16 + lr) * 32 + lk];
    #pragma unroll
    for (int i = 0; i < 4; i++) bv[i] = *(const bfv8*)&lsB[(wn + i * 16 + lr) * 32 + lk];
    #pragma unroll
    for (int i = 0; i < 4; i++)
      #pragma unroll
      for (int j = 0; j < 4; j++)
        acc[i][j] = __builtin_amdgcn_mfma_f32_16x16x32_bf16(av[i], bv[j], acc[i][j], 0, 0, 0);
    __syncthreads();
  }
  const int orow = (l >> 4) * 4, ocol = lr;
  #pragma unroll
  for (int i = 0; i < 4; i++)
    #pragma unroll
    for (int j = 0; j < 4; j++) {
      long col = n0 + wn + j * 16 + ocol;
      float bb = tB ? g.bias[col] : 0.f;
      #pragma unroll
      for (int r = 0; r < 4; r++) {
        long row = m0 + wm + i * 16 + orow + r;
        float v = acc[i][j][r] + bb;
        if (tF32) {
          long idx = (long)z * g.sCz + row * g.ldc + col;
          if (tACC) v += g.C[idx];
          g.C[idx] = v;
        }
        if (tB16) g.Cb[(long)z * g.sCbz + row * g.ldcb + col] = (bf)v;
      }
    }
}

// merged kernel: z < Zmain -> main op (tPAIR: also mirrored m-tile 2*gridDim.x-1-x);
// z >= Zmain -> special tiles. Special flat id: flat < 32*gx.spS -> op gx,
// matrix zz=flat>>5 (M=512: 4x8 tiles); else op gy (M=1024: 8x8 tiles).
template<int tB,int tF32,int tB16,int tMASK,int tACC,int tPAIR=0,int tSPEC=0,
         int sB=0,int sF32=0,int sB16=0,int sMASK=0,int sACC=0>
__global__ __launch_bounds__(256) void gemm_k(GOp g, GOp gx, GOp gy, int Zmain,
                                              const bf* __restrict__ zpg) {
  __shared__ bf lsA[4096], lsB[4096];
  int z = blockIdx.z;
  if (tSPEC && z >= Zmain) {
    int flat = (z - Zmain) * (int)(gridDim.x * gridDim.y)
             + (int)blockIdx.y * (int)gridDim.x + (int)blockIdx.x;
    if (flat >= gx.mBlk) return;
    int dxT = gx.spS * 32;
    if (flat < dxT) {
      int zz = flat >> 5, t32 = flat & 31;
      gbody<sB,sF32,sB16,sMASK,sACC>(gx, zz, (long)(t32 >> 3) * 128, (long)(t32 & 7) * 128,
                                     lsA, lsB, zpg);
    } else {
      int f = flat - dxT;
      gbody<sB,sF32,sB16,sMASK,sACC>(gy, 0, (long)(f >> 3) * 128, (long)(f & 7) * 128,
                                     lsA, lsB, zpg);
    }
  } else {
    gbody<tB,tF32,tB16,tMASK,tACC>(g, z, (long)blockIdx.x * 128, (long)blockIdx.y * 128,
                                   lsA, lsB, zpg);
    if (tPAIR)
      gbody<tB,tF32,tB16,tMASK,tACC>(g, z, (long)(2 * gridDim.x - 1 - blockIdx.x) * 128,
                                     (long)blockIdx.y * 128, lsA, lsB, zpg);
  }
}

static inline GOp mkop(const void* A, long la, long lKa, long lMa, long sAz, int zshA, int kzA,
                       const void* B, long lb, long lKb, long sBz, int zmskB, int kzB,
                       void* C, long ldc, long sCz, void* Cb, long ldcb, long sCbz,
                       const void* bias, int K) {
  GOp g;
  g.A = (const bf*)A; g.la = la; g.lKa = lKa; g.lMa = lMa; g.sAz = sAz; g.zshA = zshA; g.kzA = kzA;
  g.B = (const bf*)B; g.lb = lb; g.lKb = lKb; g.sBz = sBz; g.zmskB = zmskB; g.kzB = kzB;
  g.C = (float*)C; g.ldc = ldc; g.sCz = sCz;
  g.Cb = (bf*)Cb; g.ldcb = ldcb; g.sCbz = sCbz;
  g.bias = (const float*)bias; g.K = K; g.maskCmp = 0; g.mBlk = 0; g.spS = 0;
  return g;
}

template<int tB,int tF32,int tB16,int tMASK,int tACC,int tPAIR=0,int tSPEC=0,
         int sB=0,int sF32=0,int sB16=0,int sMASK=0,int sACC=0>
static inline void LG(hipStream_t st, int gx_, int gy_, int gz_, const GOp& g,
                      const GOp& gsx, const GOp& gsy, int Zmain, const bf* zpg) {
  gemm_k<tB,tF32,tB16,tMASK,tACC,tPAIR,tSPEC,sB,sF32,sB16,sMASK,sACC>
      <<<dim3(gx_, gy_, gz_), 256, 0, st>>>(g, gsx, gsy, Zmain, zpg);
}

// ---------------- small kernels ----------------

template<typename TI, typename TO>
__global__ __launch_bounds__(256) void k_trt(const TI* __restrict__ in, TO* __restrict__ out,
                                             long ldin, long inz, long ldout, long outz) {
  __shared__ float tile[64][65];
  int z = blockIdx.z;
  int c0 = blockIdx.x * 64, r0 = blockIdx.y * 64;
  int tx = threadIdx.x & 63, ty = threadIdx.x >> 6;
  #pragma unroll
  for (int i = ty; i < 64; i += 4) tile[i][tx] = (float)in[(long)z * inz + (long)(c0 + i) * ldin + r0 + tx];
  __syncthreads();
  #pragma unroll
  for (int i = ty; i < 64; i += 4) out[(long)z * outz + (long)(r0 + i) * ldout + c0 + tx] = (TO)tile[tx][i];
}

__global__ __launch_bounds__(256) void k_trtS(const float* __restrict__ in, bf* __restrict__ out,
                                              long ldin, long ldout, const float* __restrict__ scl) {
  __shared__ float tile[64][65];
  int c0 = blockIdx.x * 64, r0 = blockIdx.y * 64;
  int tx = threadIdx.x & 63, ty = threadIdx.x >> 6;
  #pragma unroll
  for (int i = ty; i < 64; i += 4) tile[i][tx] = in[(long)(c0 + i) * ldin + r0 + tx];
  __syncthreads();
  float sc = scl[(c0 + tx) >> 9];
  #pragma unroll
  for (int i = ty; i < 64; i += 4) out[(long)(r0 + i) * ldout + c0 + tx] = (bf)(tile[tx][i] * sc);
}

__global__ void k_scl(const float* __restrict__ evals, float* __restrict__ scl) {
  int k = threadIdx.x;
  if (k < 24) scl[k] = powf(evals[k], 0.25f);
}

__global__ void k_pvec(const float* __restrict__ evecs, bf* __restrict__ out) {
  long id = (long)blockIdx.x * 256 + threadIdx.x;
  if (id >= 24L * 16512) return;
  int kf = (int)(id / 16512);
  int rem = (int)(id % 16512);
  int c = rem / 2064, j = rem % 2064;
  int d = j - c;
  float v = (d >= 0 && d <= 1023) ? evecs[(long)(1023 - d) * 24 + kf] : 0.f;
  out[id] = (bf)v;
}

__global__ void k_mut(const float* __restrict__ mul_, bf* __restrict__ out) {
  long id = (long)blockIdx.x * 256 + threadIdx.x;  // < 786432
  long r = id >> 9; int d = (int)(id & 511);
  int i = (int)(r >> 9), o = (int)(r & 511);
  out[id] = (bf)mul_[(long)o * 1536 + d * 3 + i];
}

// PT layout init: PT[1] = [A|B] = myl (at block 15), PT[0] = [I|0] (block 16),
// TRSa = (CM^1)^T = [myl^T | [I;0]]
__global__ __launch_bounds__(256) void k_prep(const float* __restrict__ myl,
                                              bf* __restrict__ ptop, bf* __restrict__ trs) {
  __shared__ float t[64][65];
  long bid = blockIdx.x;
  if (bid < 768) {
    long id = bid * 2048 + (long)threadIdx.x * 8;
    #pragma unroll
    for (int u = 0; u < 8; ++u) {
      long i = id + u;
      if (i < 524288) {                      // PT[1] = myl
        ptop[15L * 524288 + i] = (bf)myl[i];
      } else if (i < 1048576) {              // PT[0] = [I | 0]
        long i2 = i - 524288;
        int p = (int)(i2 >> 10), q = (int)(i2 & 1023);
        ptop[16L * 524288 + i2] = (bf)((q == p) ? 1.f : 0.f);
      } else {                               // TRS right half [1024][512..]
        long i3 = i - 1048576;
        int x = (int)(i3 >> 9), y = (int)(i3 & 511);
        trs[(long)x * 1024 + 512 + y] = (bf)((x == y) ? 1.f : 0.f);
      }
    }
  } else {
    int tile = (int)(bid - 768);             // 128 tiles: TRS left = myl^T
    int txx = tile >> 3, tyy = tile & 7;
    int lx = threadIdx.x & 63, ly = threadIdx.x >> 6;
    #pragma unroll
    for (int i = ly; i < 64; i += 4)
      t[i][lx] = myl[(long)(tyy * 64 + i) * 1024 + txx * 64 + lx];
    __syncthreads();
    #pragma unroll
    for (int i = ly; i < 64; i += 4)
      trs[(long)(txx * 64 + i) * 1024 + tyy * 64 + lx] = (bf)t[lx][i];
  }
}

__global__ __launch_bounds__(256) void k_ln(const float* __restrict__ x, const float* __restrict__ sc,
                                            const float* __restrict__ bi, bf* __restrict__ hb) {
  __shared__ float red[8];
  long row = blockIdx.x;
  const float* xr = x + row * 512;
  int t = threadIdx.x;
  float a = xr[t], b2 = xr[t + 256];
  float s = a + b2;
  #pragma unroll
  for (int o = 32; o; o >>= 1) s += __shfl_down(s, o, 64);
  if ((t & 63) == 0) red[t >> 6] = s;
  __syncthreads();
  float mu = (red[0] + red[1] + red[2] + red[3]) * (1.f / 512.f);
  __syncthreads();
  float c1 = a - mu, c2 = b2 - mu;
  float qq = c1 * c1 + c2 * c2;
  #pragma unroll
  for (int o = 32; o; o >>= 1) qq += __shfl_down(qq, o, 64);
  if ((t & 63) == 0) red[t >> 6] = qq;
  __syncthreads();
  float var = (red[0] + red[1] + red[2] + red[3]) * (1.f / 512.f);
  float rs = rsqrtf(var + 1e-5f);
  hb[row * 512 + t]       = (bf)(c1 * rs * sc[t] + bi[t]);
  hb[row * 512 + t + 256] = (bf)(c2 * rs * sc[t + 256] + bi[t + 256]);
}

__global__ void k_deltasS(const float* __restrict__ dp, long stride, int S,
                          const bf* __restrict__ callb, bf* __restrict__ db) {
  long id = (long)blockIdx.x * 256 + threadIdx.x;  // < 2097152
  int o = (int)(id & 511); long row = id >> 9; int tt = (int)(row & 1023);
  float v = 0.f;
  for (int zz = 0; zz < S; ++zz) v += dp[(long)zz * stride + id];
  for (int i = 0; i < 3; ++i)
    if (tt >= i) v += (float)callb[(row - i) * 1536 + i * 512 + o];
  db[id] = (bf)v;
}

__global__ void k_egather(const float* __restrict__ dp, long stride, int S,
                          float* __restrict__ E, bf* __restrict__ eb0) {
  long id = (long)blockIdx.x * 256 + threadIdx.x;  // < 262144
  int p = (int)(id & 1023); long r = id >> 10;
  int b = (int)(r >> 6), c = (int)(r & 63);
  int tq = c * 16 + ((p < 512) ? 15 : 14);
  long idx = ((long)(b << 10) + tq) * 512 + (p & 511);
  float v = 0.f;
  for (int zz = 0; zz < S; ++zz) v += dp[(long)zz * stride + idx];
  E[id] = v; eb0[id] = (bf)v;
}

// per-batch exclusive shift: ssb[b*64+c] = (c>0)? E[b*64+c-1] : 0
__global__ void k_sfinal(const float* __restrict__ E, bf* __restrict__ ssb) {
  long id = (long)blockIdx.x * 256 + threadIdx.x;  // < 262144
  int c = (int)((id >> 10) & 63);
  ssb[id] = (c > 0) ? (bf)E[id - 1024] : (bf)0.f;
}

__global__ void k_combgelu(const float* __restrict__ dp, long stride, int S,
                           const bf* __restrict__ outh, bf* __restrict__ yg) {
  long id = (long)blockIdx.x * 256 + threadIdx.x;  // < 2097152
  int o = (int)(id & 511); long row = id >> 9;
  int b = (int)(row >> 10), tt = (int)(row & 1023);
  int c = tt >> 4, j = tt & 15;
  long wv = ((long)(j * 512 + o)) * 256 + b * 64 + c;
  float v = (float)outh[wv];
  for (int zz = 0; zz < S; ++zz) v += dp[(long)zz * stride + id];
  yg[id] = (bf)(0.5f * v * (1.f + erff(v * 0.70710678118654752f)));
}

__global__ void k_glures(const bf* __restrict__ g, float* __restrict__ x) {
  long id = (long)blockIdx.x * 256 + threadIdx.x;  // < 2097152
  int o = (int)(id & 511); long row = id >> 9;
  float a = (float)g[row * 1024 + o], bb = (float)g[row * 1024 + 512 + o];
  x[id] = x[id] + a / (1.f + expf(-bb));
}

__global__ void k_cast(const float* __restrict__ in, bf* __restrict__ out, long n4) {
  long id = (long)blockIdx.x * 256 + threadIdx.x;
  if (id >= n4) return;
  float4 v = *(const float4*)(in + id * 4);
  bfv4 o; o[0] = (bf)v.x; o[1] = (bf)v.y; o[2] = (bf)v.z; o[3] = (bf)v.w;
  *(bfv4*)(out + id * 4) = o;
}

__global__ void k_fill(float* p, long n, float v) {
  long id = (long)blockIdx.x * 256 + threadIdx.x;
  if (id < n) p[id] = v;
}

// ---------------- workspace layout (byte offsets) ----------------
struct Lay {
  long ZPG, SSTB, SCL, EMBT, PROJT, PVEC, PTOP, TRS, WU, X, MPHITL, MUTL, W1TL,
       HB, HTB, DSLOT, DP, RC, E, EB0, EB1, need;
  int nk, S;
};
static Lay mkLay(int nk, int S) {
  Lay L; long o = 0;
  auto al = [&](long sz) { long r = o; o += (sz + 255) & ~255L; return r; };
  L.nk = nk; L.S = S;
  L.ZPG   = al(4096);
  L.SSTB  = al(524288);
  L.SCL   = al(256);
  L.EMBT  = al(524288);
  L.PROJT = al(524288);
  L.PVEC  = al(24L * 16512 * 2);
  L.PTOP  = al(17L * 1048576);           // PT[i] tops, descending powers
  L.TRS   = al(2L * 2097152);            // TRSa | TRSb
  L.WU    = al(8388608);                 // WUa(W,U) | WUb(W,U)
  L.X     = al(8388608);
  L.MPHITL= al(12582912);
  L.MUTL  = al(1572864);
  L.W1TL  = al(1048576);
  L.HB    = al(4194304);
  L.HTB   = al(4194304);
  L.DSLOT = al(4194304);                 // DELTAB | YGB
  L.DP    = al((long)S * 8388608);
  long rc = (long)nk * 4194304;          // XTC
  if (rc < 16777216) rc = 16777216;      // CALLB + OUTH ; G
  L.RC    = al(rc);
  L.E     = al(1048576);
  L.EB0   = al(524288);
  L.EB1   = al(524288);
  L.need  = o;
  return L;
}

extern "C" void kernel_launch(void* const* d_in, const int* in_sizes, int n_in,
                              void* d_out, int out_size, void* d_ws, size_t ws_size,
                              hipStream_t stream) {
  Lay L = mkLay(12, 4);                        // ~155 MB (proven fit, round 13)
  if (L.need > (long)ws_size) L = mkLay(8, 4); // ~138 MB
  if (L.need > (long)ws_size) L = mkLay(4, 2); // ~104 MB
  if (L.need > (long)ws_size) {
    k_fill<<<8192, 256, 0, stream>>>((float*)d_out, 2097152, 1.0e6f + (float)(ws_size >> 20));
    return;
  }
  const float* inp  = (const float*)d_in[0];
  const float* embw = (const float*)d_in[1];
  const float* embb = (const float*)d_in[2];
  const float* lns  = (const float*)d_in[3];
  const float* lnb  = (const float*)d_in[4];
  const float* m_y  = (const float*)d_in[5];
  const float* m_u  = (const float*)d_in[6];
  const float* mphi = (const float*)d_in[7];
  const float* w1   = (const float*)d_in[8];
  const float* b1   = (const float*)d_in[9];
  const float* pw   = (const float*)d_in[10];
  const float* pb   = (const float*)d_in[11];
  const float* evals = (const float*)d_in[12];
  const float* evecs = (const float*)d_in[13];

  char* w = (char*)d_ws;
  bf*    ZPG   = (bf*)(w + L.ZPG);
  bf*    SSTB  = (bf*)(w + L.SSTB);
  float* SCL   = (float*)(w + L.SCL);
  bf*    EMBT  = (bf*)(w + L.EMBT);
  bf*    PROJT = (bf*)(w + L.PROJT);
  bf*    PVEC  = (bf*)(w + L.PVEC);
  bf*    PTOP  = (bf*)(w + L.PTOP);      // PT(i) = PTOP + (16-i)*524288
  bf*    TRSa  = (bf*)(w + L.TRS);
  bf*    TRSb  = TRSa + 1048576;
  bf*    WUa   = (bf*)(w + L.WU);
  bf*    WUb   = (bf*)(w + L.WU + 4194304);
  float* X     = (float*)(w + L.X);
  bf*    MPHITL= (bf*)(w + L.MPHITL);
  bf*    MUTL  = (bf*)(w + L.MUTL);
  bf*    W1TL  = (bf*)(w + L.W1TL);
  bf*    HB    = (bf*)(w + L.HB);
  bf*    HTB   = (bf*)(w + L.HTB);
  bf*    DELTAB= (bf*)(w + L.DSLOT);
  bf*    YGB   = (bf*)(w + L.DSLOT);
  float* DP    = (float*)(w + L.DP);
  bf*    XTC   = (bf*)(w + L.RC);
  bf*    CALLB = (bf*)(w + L.RC);
  bf*    OUTH  = (bf*)(w + L.RC + 12582912);
  bf*    G     = (bf*)(w + L.RC);
  float* E     = (float*)(w + L.E);
  bf*    EB0   = (bf*)(w + L.EB0);
  bf*    EB1   = (bf*)(w + L.EB1);
  bf*    INB   = HB;
  hipStream_t st = stream;
  const int nk = L.nk, S = L.S, nchunk = 24 / nk;
  const long DPS = 2097152;
  const int Kcphi = nk * 512 / S, kzphi = Kcphi >> 9;
  const int Kcy = 8192 / S, kzy = Kcy >> 9;
  GOp gnull = {};
  const int BIGZ = 1 << 30;

  hipMemsetAsync(w + L.ZPG, 0, 4096, st);

  // ---- one-time prep ----
  k_scl<<<1, 32, 0, st>>>(evals, SCL);
  k_pvec<<<1549, 256, 0, st>>>(evecs, PVEC);
  k_trt<float, bf><<<dim3(8, 8, 1), 256, 0, st>>>(embw, EMBT, 512, 0, 512, 0);
  k_trt<float, bf><<<dim3(8, 8, 1), 256, 0, st>>>(pw, PROJT, 512, 0, 512, 0);
  k_cast<<<2048, 256, 0, st>>>(inp, INB, 524288);
  LG<1,1,0,0,0>(st, 32, 4, 1,
      mkop(INB, 512, 512, 262144, 0, 30, 0, EMBT, 512, 512, 0, 0, 0,
           X, 512, 0, nullptr, 0, 0, embb, 512), gnull, gnull, BIGZ, ZPG);

  for (int l = 0; l < 4; ++l) {
    // --- PT init + (CM^1)^T ---
    k_prep<<<896, 256, 0, st>>>(m_y + (long)l * 524288, PTOP, TRSa);
    // --- per-layer weight prep ---
    k_trtS<<<dim3(192, 8, 1), 256, 0, st>>>(mphi + (long)l * 6291456, MPHITL, 512, 12288, SCL);
    k_mut<<<3072, 256, 0, st>>>(m_u + (long)l * 786432, MUTL);
    k_trt<float, bf><<<dim3(8, 16, 1), 256, 0, st>>>(w1 + (long)l * 524288, W1TL, 1024, 0, 512, 0);

    // --- LN -> HB ; HTB per-batch transpose ---
    k_ln<<<4096, 256, 0, st>>>(X, lns + l * 512, lnb + l * 512, HB);
    k_trt<bf, bf><<<dim3(16, 8, 4), 256, 0, st>>>(HB, HTB, 512, 524288, 1024, 524288);

    // --- spectral conv (paired m-tiles) + phi; doubling rides r=0..3 ---
    int hostRound = 0;
    auto mkDXY = [&](int s, bf* TRScur, bf* TRSnxt, GOp& dx, GOp& dy) {
      // dx: PT[s+1+zz] = PT[1+zz] * (CM^s)^T^T  (M=512, 32 tiles each, zz<s)
      dx = mkop(PTOP + 15L * 524288, 1024, 512, 0, -524288L, 0, 0,
                TRScur, 1024, 512, 0, 0, 0,
                nullptr, 0, 0, PTOP + (long)(15 - s) * 524288, 1024, -524288L,
                nullptr, 1024);
      dx.mBlk = 32 * s + 64; dx.spS = s;
      // dy: TRSnxt = (CM^{2s})^T = TRScur * CM^s^T^T  (64 tiles, M=1024)
      dy = mkop(TRScur, 1024, 512, 524288, 0, 0, 0,
                PTOP + (long)(16 - s) * 524288, 1024, 512, 0, 0, 0,
                nullptr, 0, 0, TRSnxt, 1024, 0, nullptr, 1024);
    };
    for (int kc = 0; kc < nchunk; ++kc) {
      GOp gconv = mkop(PVEC + (long)kc * nk * 16512, 0, 0, 0, 16512, 2, 0,
                       HTB, 1024, 512, 524288, 3, 0,
                       nullptr, 0, 0, XTC, 512, 524288, nullptr, 1024);
      if (hostRound < 4) {
        int s = 1 << hostRound;
        bf* TRScur = (hostRound & 1) ? TRSb : TRSa;
        bf* TRSnxt = (hostRound & 1) ? TRSa : TRSb;
        GOp dx, dy; mkDXY(s, TRScur, TRSnxt, dx, dy);
        int nzs = (dx.mBlk + 15) / 16;            // 4x4 tiles per ride z
        LG<0,0,1,3,0, 1,1, 0,0,1,0,0>(st, 4, 4, 4 * nk + nzs, gconv, dx, dy, 4 * nk, ZPG);
        ++hostRound;
      } else {
        LG<0,0,1,3,0, 1,0>(st, 4, 4, 4 * nk, gconv, gnull, gnull, BIGZ, ZPG);
      }
      GOp gphi = mkop(XTC, 512, 2097152, 262144, 0, 30, kzphi,
                      MPHITL + (long)kc * nk * 512, 12288, 512, 0, 0, kzphi,
                      DP, 512, DPS, nullptr, 0, 0, nullptr, Kcphi);
      if (hostRound < 4) {
        int s = 1 << hostRound;
        bf* TRScur = (hostRound & 1) ? TRSb : TRSa;
        bf* TRSnxt = (hostRound & 1) ? TRSa : TRSb;
        GOp dx, dy; mkDXY(s, TRScur, TRSnxt, dx, dy);
        int nzs = (dx.mBlk + 127) / 128;
        if (kc == 0) LG<0,1,0,0,0, 0,1, 0,0,1,0,0>(st, 32, 4, S + nzs, gphi, dx, dy, S, ZPG);
        else         LG<0,1,0,0,1, 0,1, 0,0,1,0,0>(st, 32, 4, S + nzs, gphi, dx, dy, S, ZPG);
        ++hostRound;
      } else {
        if (kc == 0) LG<0,1,0,0,0>(st, 32, 4, S, gphi, gnull, gnull, BIGZ, ZPG);
        else         LG<0,1,0,0,1>(st, 32, 4, S, gphi, gnull, gnull, BIGZ, ZPG);
      }
    }

    // --- AR terms + deltas ---
    LG<0,0,1,0,0>(st, 32, 12, 1,
        mkop(HB, 512, 512, 262144, 0, 30, 0, MUTL, 512, 512, 0, 0, 0,
             nullptr, 0, 0, CALLB, 1536, 0, nullptr, 512), gnull, gnull, BIGZ, ZPG);
    k_deltasS<<<8192, 256, 0, st>>>(DP, DPS, S, CALLB, DELTAB);

    // --- local solutions: causal im2col x PT blocks (desc), split-K into DP ---
    LG<0,1,0,1,0>(st, 32, 4, S,
        mkop(DELTAB, 512, -512, 262144, 0, 30, kzy,
             PTOP + 16L * 524288, 1024, -524288L, 0, 0, kzy,
             DP, 512, DPS, nullptr, 0, 0, nullptr, Kcy), gnull, gnull, BIGZ, ZPG);

    // --- Kogge-Stone scan: merged {W/U squaring | E-update}; k=5 skips U ---
    k_egather<<<1024, 256, 0, st>>>(DP, DPS, S, E, EB0);
    const bf* Wc = PTOP;                          // W^1 = CM^16 = [PT16; PT15]
    const bf* Uc = TRSa;                          // U^1 = (CM^16)^T (after r3)
    bf* EBc = EB0; bf* EBn = EB1;
    bf* WUn = WUa;
    for (int k = 1; k <= 5; ++k) {
      int sh = 1 << (k - 1);
      GOp mn = mkop(Wc, 1024, 512, 524288, (long)(Uc - Wc), 0, 0,
                    Uc, 1024, 512, (long)(Wc - Uc), 1, 0,
                    nullptr, 0, 0, WUn, 1024, 1048576, nullptr, 1024);
      GOp sp = mkop(EBc - (long)sh * 1024, 1024, 512, 524288, 0, 30, 0,
                    Wc, 1024, 512, 0, 0, 0,
                    E, 1024, 0, EBn, 1024, 0, nullptr, 1024);
      sp.maskCmp = sh; sp.mBlk = 16; sp.spS = 99;
      int gzN = (k < 5) ? 3 : 2, zm = (k < 5) ? 2 : 1;
      LG<0,0,1,0,0, 0,1, 0,1,1,2,1>(st, 8, 8, gzN, mn, sp, gnull, zm, ZPG);
      Wc = WUn; Uc = WUn + 1048576;
      WUn = (k & 1) ? WUb : WUa;
      bf* tmp = EBc; EBc = EBn; EBn = tmp;
    }
    GOp fe = mkop(EBc - 32L * 1024, 1024, 512, 524288, 0, 30, 0,
                  Wc, 1024, 512, 0, 0, 0,
                  E, 1024, 0, nullptr, 0, 0, nullptr, 1024);
    fe.maskCmp = 32;
    LG<0,1,0,2,1>(st, 2, 8, 1, fe, gnull, gnull, BIGZ, ZPG);
    k_sfinal<<<1024, 256, 0, st>>>(E, SSTB);

    // --- homogeneous completion (A = PT tops, desc) + gelu + MLP(GLU) ---
    LG<0,0,1,0,0>(st, 64, 2, 1,
        mkop(PTOP + 15L * 524288, 1024, 512, -524288L, 0, 30, 0,
             SSTB, 1024, 512, 0, 0, 0,
             nullptr, 0, 0, OUTH, 256, 0, nullptr, 1024), gnull, gnull, BIGZ, ZPG);
    k_combgelu<<<8192, 256, 0, st>>>(DP, DPS, S, OUTH, YGB);
    LG<1,0,1,0,0>(st, 32, 8, 1,
        mkop(YGB, 512, 512, 262144, 0, 30, 0, W1TL, 512, 512, 0, 0, 0,
             nullptr, 0, 0, G, 1024, 0, b1 + (long)l * 1024, 512), gnull, gnull, BIGZ, ZPG);
    k_glures<<<8192, 256, 0, st>>>(G, X);
  }

  // ---- output projection ----
  k_cast<<<2048, 256, 0, st>>>(X, INB, 524288);
  LG<1,1,0,0,0>(st, 32, 4, 1,
      mkop(INB, 512, 512, 262144, 0, 30, 0, PROJT, 512, 512, 0, 0, 0,
           (float*)d_out, 512, 0, nullptr, 0, 0, pb, 512), gnull, gnull, BIGZ, ZPG);
}